// Round 9
// baseline (279.178 us; speedup 1.0000x reference)
//
#include <hip/hip_runtime.h>

#define BATCH 64
#define SEQ   128
#define NLAB  32
#define NEGF  -3.0e38f

// ---------------------------------------------------------------------------
// Kernel 1 (v4): pot + gold partials + inline len.
// One thread per 8 labels of a cell-quarter; coalesced float4 loads +
// wave-private LDS transpose (as v3). Gold: per-block partial -> gpart[blk]
// (no atomics, no zeroing). len computed inline only in blocks owning row 0.
// ---------------------------------------------------------------------------
__global__ __launch_bounds__(256) void pot_gold_kernel(
    const float* __restrict__ logits, const int* __restrict__ labels,
    float* __restrict__ pot, float* __restrict__ gpart)
{
    const int tid = threadIdx.x;
    const int wave = tid >> 6, lane = tid & 63;
    __shared__ __align__(16) float LP[4 * 16 * 36];   // 9216 B
    __shared__ float gred[4];
    __shared__ int s_len;
    float* W = LP + wave * (16 * 36);

    const int block_cell0 = blockIdx.x * 256;         // 256 cells per block
    const int b = block_cell0 >> 14;
    const bool has_row0 = (blockIdx.x & 63) == 0;     // this block owns rows 0,1

    if (has_row0 && tid < 64) {                       // len[b] from labels[b,0,:]
        const size_t base = (size_t)b << 14;
        int cnt = (labels[base + tid] != -100) + (labels[base + 64 + tid] != -100);
        #pragma unroll
        for (int d = 32; d; d >>= 1) cnt += __shfl_down(cnt, d, 64);
        if (tid == 0) s_len = cnt;
    }
    __syncthreads();
    const int len = has_row0 ? s_len : -1;            // only ci==0 cells use it

    float gacc = 0.0f;
    const int wave_cell0 = block_cell0 + wave * 64;

    #pragma unroll
    for (int chunk = 0; chunk < 4; ++chunk) {
        const int c0 = wave_cell0 + chunk * 16;       // 16 cells this chunk
        const float4* src = reinterpret_cast<const float4*>(logits) + ((size_t)c0 << 3);
        const float4 f0 = src[lane];
        const float4 f1 = src[lane + 64];
        const int lv = (lane < 16) ? labels[c0 + lane] : 0;

        {   // scatter to LDS: quad q -> cell q>>3, slot q&7
            const int cA = lane >> 3, tA = lane & 7;
            *reinterpret_cast<float4*>(W + cA * 36 + tA * 4) = f0;
            const int q1 = lane + 64;
            const int cB = q1 >> 3, tB = q1 & 7;
            *reinterpret_cast<float4*>(W + cB * 36 + tB * 4) = f1;
        }
        const int c = lane >> 2, u = lane & 3;        // cell, quarter
        const float4 r0 = *reinterpret_cast<const float4*>(W + c * 36 + u * 8);
        const float4 r1 = *reinterpret_cast<const float4*>(W + c * 36 + u * 8 + 4);

        int lab = __shfl(lv, c, 64);
        if (lab < 0) lab = 0;
        const float l0 = __shfl(r0.x, c << 2, 64);    // logits[cell][0]

        const int cell = c0 + c;
        const int ci = (cell >> 7) & (SEQ - 1);
        const int cj = cell & (SEQ - 1);
        const bool special = (ci == 0) && (cj == len - 1);

        const float vv[8] = { r0.x, r0.y, r0.z, r0.w, r1.x, r1.y, r1.z, r1.w };
        float m = NEGF, g = 0.0f;
        #pragma unroll
        for (int e = 0; e < 8; ++e) {
            const int l = u * 8 + e;
            const float r = vv[e] - l0;
            const bool isg = (l == lab);
            g = isg ? r : g;
            float cand = r + (isg ? 0.0f : 1.0f);
            if (l == 0 && special) cand -= 1.0e9f;
            m = fmaxf(m, cand);
        }
        m = fmaxf(m, __shfl_xor(m, 1, 64));
        m = fmaxf(m, __shfl_xor(m, 2, 64));
        g += __shfl_xor(g, 1, 64);
        g += __shfl_xor(g, 2, 64);
        if (u == 0) {
            pot[cell] = m;
            gacc += g;
        }
    }

    #pragma unroll
    for (int d = 1; d < 64; d <<= 1) gacc += __shfl_xor(gacc, d, 64);
    if (lane == 0) gred[wave] = gacc;
    __syncthreads();
    if (tid == 0)
        gpart[blockIdx.x] = gred[0] + gred[1] + gred[2] + gred[3];
}

// ---------------------------------------------------------------------------
// Kernel 2 (v7b): max-plus CKY with prework/tail split.
//   A [i][k] pitch 132 : best span starting at i, width k (holds pot til step k)
//   Bt[j][c] pitch 132 : c = N-1-width (contiguous-in-k at each step)
// Step wn, entry i (group of 4 lanes, TPE=4 for ALL steps):
//   TAIL (after barrier): only terms touching step-(wn-1) outputs:
//     k=0   : a0 + Bt[j][N-wn]          (ONE b32 broadcast read)
//     k=wn-1: val(reg) + awB(prefetched width-0 term)
//   combined with pre-reduced bulk max pre_m -> val = max + potv(prefetched);
//   all operands group-uniform => NO shuffles in tail.
//   PREWORK (before barrier, for step wn+1): bulk max over k in [1,wn-1]
//   (data >= 1 step old => race-free; masked elements may race benignly),
//   2-shuffle butterfly, prefetch potv/awB. S = (-(wn+1))&3 B-alignment.
// R8 FIX: awB = Brow[wn] (width-0 col c=N-1), was Brow[wn+1] (NEGF pad).
// ---------------------------------------------------------------------------
template<int S>
__device__ __forceinline__ void cky_step(
    float* __restrict__ A, float* __restrict__ Bt, const int wn,
    const int i, const int s, float& pre_m, float& val, float& potv,
    float& awB, const float a0)
{
    const int iw = i + wn;
    if (iw < SEQ) {
        const float newB = Bt[iw * 132 + (SEQ - wn)];        // step-(wn-1) output
        const float m = fmaxf(pre_m, fmaxf(a0 + newB, val + awB));
        val = m + potv;
        if (s == 0) {
            A[i * 132 + wn] = val;
            Bt[iw * 132 + (SEQ - 1 - wn)] = val;
        }
    }
    if (iw + 1 < SEQ) {      // prework for step wn+1
        const float* Arow = A + i * 132;
        potv = Arow[wn + 1];                                  // pot, old
        const float* Brow = Bt + (iw + 1) * 132 + (SEQ - wn - 1); // k=0 col
        awB = Brow[wn];                                       // width-0 (c=N-1)
        const int kmax = wn - 1;                              // bulk k in [1,kmax]
        float pm = NEGF;
        #pragma unroll 2
        for (int q = s; (q << 2) <= kmax; q += 4) {
            const int k0 = q << 2;
            float4 a = *reinterpret_cast<const float4*>(Arow + k0);
            const float* bp = Brow + k0;                      // ≡ S (mod 4)
            float b0, b1, b2, b3;
            if (S == 0) {
                const float4 bv = *reinterpret_cast<const float4*>(bp);
                b0 = bv.x; b1 = bv.y; b2 = bv.z; b3 = bv.w;
            } else if (S == 2) {
                const float2 u0 = *reinterpret_cast<const float2*>(bp);
                const float2 u1 = *reinterpret_cast<const float2*>(bp + 2);
                b0 = u0.x; b1 = u0.y; b2 = u1.x; b3 = u1.y;
            } else {                     // S==1: bp+1 ≡ 2; S==3: bp+1 ≡ 0
                b0 = bp[0];
                const float2 u = *reinterpret_cast<const float2*>(bp + 1);
                b1 = u.x; b2 = u.y;
                b3 = bp[3];
            }
            a.x = (k0 != 0)        ? a.x : NEGF;   // k=0 handled in tail
            a.y = (k0 + 1 <= kmax) ? a.y : NEGF;
            a.z = (k0 + 2 <= kmax) ? a.z : NEGF;
            a.w = (k0 + 3 <= kmax) ? a.w : NEGF;
            pm = fmaxf(pm, fmaxf(fmaxf(a.x + b0, a.y + b1),
                                 fmaxf(a.z + b2, a.w + b3)));
        }
        pm = fmaxf(pm, __shfl_xor(pm, 1, 4));
        pm = fmaxf(pm, __shfl_xor(pm, 2, 4));
        pre_m = pm;
    } else {
        pre_m = NEGF;
    }
    __syncthreads();
}

__global__ __launch_bounds__(512, 1) void cky_kernel(
    const float* __restrict__ pot, const float* __restrict__ gpart,
    const int* __restrict__ labels, float* __restrict__ out)
{
    const int b = blockIdx.x;
    const int tid = threadIdx.x;
    const float* p = pot + (size_t)b * SEQ * SEQ;

    __shared__ __align__(16) float A[SEQ * 132];      // 67584 B
    __shared__ __align__(16) float Bt[SEQ * 132];     // 67584 B
    __shared__ int s_len;
    __shared__ float s_gold;

    if (tid < 64) {                                   // len[b]
        const size_t base = (size_t)b << 14;
        int cnt = (labels[base + tid] != -100) + (labels[base + 64 + tid] != -100);
        #pragma unroll
        for (int d = 32; d; d >>= 1) cnt += __shfl_down(cnt, d, 64);
        if (tid == 0) s_len = cnt;
    } else if (tid < 128) {                           // gold[b] from partials
        float g = gpart[b * 64 + (tid - 64)];
        #pragma unroll
        for (int d = 32; d; d >>= 1) g += __shfl_down(g, d, 64);
        if (tid == 64) s_gold = g;
    }

    {   // NEGF-fill both tables (pads must read as ~NEGF)
        const float4 neg4 = make_float4(NEGF, NEGF, NEGF, NEGF);
        float4* a4 = reinterpret_cast<float4*>(A);
        float4* b4 = reinterpret_cast<float4*>(Bt);
        for (int idx = tid; idx < SEQ * 132 / 4; idx += 512) {
            a4[idx] = neg4; b4[idx] = neg4;
        }
    }
    __syncthreads();
    {   // scatter pot into both tables (coalesced global float4 reads)
        const float4* p4 = reinterpret_cast<const float4*>(p);
        for (int qi = tid; qi < SEQ * SEQ / 4; qi += 512) {
            const int i = qi >> 5;
            const int j0 = (qi & 31) << 2;
            const float4 v = p4[qi];
            const float vv[4] = { v.x, v.y, v.z, v.w };
            #pragma unroll
            for (int c2 = 0; c2 < 4; ++c2) {
                const int j = j0 + c2;
                if (j >= i) {
                    A[i * 132 + (j - i)] = vv[c2];
                    Bt[j * 132 + (SEQ - 1 - (j - i))] = vv[c2];
                }
            }
        }
    }
    __syncthreads();

    const int i = tid >> 2, s = tid & 3;
    // bootstrap state for step wn=1
    float pre_m = NEGF, val = 0.0f, potv = 0.0f, awB = 0.0f, a0 = 0.0f;
    if (i + 1 < SEQ) {
        const float* Arow = A + i * 132;
        a0   = Arow[0];                 // A[i][0] = term(i), constant
        val  = a0;                      // stands in for A[i][wn-1] at wn=1
        potv = Arow[1];                 // pot[i][i+1]
        awB  = Bt[(i + 1) * 132 + (SEQ - 1)];  // term(i+1)
    }

    int wn = 1;
    #pragma unroll 1
    for (int ph = 0; ph < 31; ++ph) {   // wn = 1..124
        cky_step<2>(A, Bt, wn,     i, s, pre_m, val, potv, awB, a0);
        cky_step<1>(A, Bt, wn + 1, i, s, pre_m, val, potv, awB, a0);
        cky_step<0>(A, Bt, wn + 2, i, s, pre_m, val, potv, awB, a0);
        cky_step<3>(A, Bt, wn + 3, i, s, pre_m, val, potv, awB, a0);
        wn += 4;
    }
    cky_step<2>(A, Bt, 125, i, s, pre_m, val, potv, awB, a0);
    cky_step<1>(A, Bt, 126, i, s, pre_m, val, potv, awB, a0);
    cky_step<0>(A, Bt, 127, i, s, pre_m, val, potv, awB, a0);

    if (tid == 0) {
        const int len = s_len;
        const float pred = A[len - 1];        // A[0][len-1]
        const float margin = fmaxf(pred - s_gold, 0.0f);
        atomicAdd(out, margin * (1.0f / (float)BATCH));
    }
}

extern "C" void kernel_launch(void* const* d_in, const int* in_sizes, int n_in,
                              void* d_out, int out_size, void* d_ws, size_t ws_size,
                              hipStream_t stream) {
    const float* logits = (const float*)d_in[0];
    const int* labels = (const int*)d_in[1];
    float* out = (float*)d_out;

    float* pot = (float*)d_ws;                          // B*N*N floats = 4 MB
    float* gpart = pot + (size_t)BATCH * SEQ * SEQ;     // 4096 floats

    (void)hipMemsetAsync(out, 0, sizeof(float), stream);

    pot_gold_kernel<<<BATCH * SEQ * SEQ / 256, 256, 0, stream>>>(
        logits, labels, pot, gpart);
    cky_kernel<<<BATCH, 512, 0, stream>>>(pot, gpart, labels, out);
}

// Round 10
// 259.651 us; speedup vs baseline: 1.0752x; 1.0752x over previous
//
#include <hip/hip_runtime.h>

#define BATCH 64
#define SEQ   128
#define NLAB  32
#define NEGF  -3.0e38f
#define PA    132

// ---------------------------------------------------------------------------
// Kernel 1 (v4): pot + gold partials + inline len. (unchanged from R9)
// ---------------------------------------------------------------------------
__global__ __launch_bounds__(256) void pot_gold_kernel(
    const float* __restrict__ logits, const int* __restrict__ labels,
    float* __restrict__ pot, float* __restrict__ gpart)
{
    const int tid = threadIdx.x;
    const int wave = tid >> 6, lane = tid & 63;
    __shared__ __align__(16) float LP[4 * 16 * 36];   // 9216 B
    __shared__ float gred[4];
    __shared__ int s_len;
    float* W = LP + wave * (16 * 36);

    const int block_cell0 = blockIdx.x * 256;
    const int b = block_cell0 >> 14;
    const bool has_row0 = (blockIdx.x & 63) == 0;

    if (has_row0 && tid < 64) {
        const size_t base = (size_t)b << 14;
        int cnt = (labels[base + tid] != -100) + (labels[base + 64 + tid] != -100);
        #pragma unroll
        for (int d = 32; d; d >>= 1) cnt += __shfl_down(cnt, d, 64);
        if (tid == 0) s_len = cnt;
    }
    __syncthreads();
    const int len = has_row0 ? s_len : -1;

    float gacc = 0.0f;
    const int wave_cell0 = block_cell0 + wave * 64;

    #pragma unroll
    for (int chunk = 0; chunk < 4; ++chunk) {
        const int c0 = wave_cell0 + chunk * 16;
        const float4* src = reinterpret_cast<const float4*>(logits) + ((size_t)c0 << 3);
        const float4 f0 = src[lane];
        const float4 f1 = src[lane + 64];
        const int lv = (lane < 16) ? labels[c0 + lane] : 0;

        {
            const int cA = lane >> 3, tA = lane & 7;
            *reinterpret_cast<float4*>(W + cA * 36 + tA * 4) = f0;
            const int q1 = lane + 64;
            const int cB = q1 >> 3, tB = q1 & 7;
            *reinterpret_cast<float4*>(W + cB * 36 + tB * 4) = f1;
        }
        const int c = lane >> 2, u = lane & 3;
        const float4 r0 = *reinterpret_cast<const float4*>(W + c * 36 + u * 8);
        const float4 r1 = *reinterpret_cast<const float4*>(W + c * 36 + u * 8 + 4);

        int lab = __shfl(lv, c, 64);
        if (lab < 0) lab = 0;
        const float l0 = __shfl(r0.x, c << 2, 64);

        const int cell = c0 + c;
        const int ci = (cell >> 7) & (SEQ - 1);
        const int cj = cell & (SEQ - 1);
        const bool special = (ci == 0) && (cj == len - 1);

        const float vv[8] = { r0.x, r0.y, r0.z, r0.w, r1.x, r1.y, r1.z, r1.w };
        float m = NEGF, g = 0.0f;
        #pragma unroll
        for (int e = 0; e < 8; ++e) {
            const int l = u * 8 + e;
            const float r = vv[e] - l0;
            const bool isg = (l == lab);
            g = isg ? r : g;
            float cand = r + (isg ? 0.0f : 1.0f);
            if (l == 0 && special) cand -= 1.0e9f;
            m = fmaxf(m, cand);
        }
        m = fmaxf(m, __shfl_xor(m, 1, 64));
        m = fmaxf(m, __shfl_xor(m, 2, 64));
        g += __shfl_xor(g, 1, 64);
        g += __shfl_xor(g, 2, 64);
        if (u == 0) {
            pot[cell] = m;
            gacc += g;
        }
    }

    #pragma unroll
    for (int d = 1; d < 64; d <<= 1) gacc += __shfl_xor(gacc, d, 64);
    if (lane == 0) gred[wave] = gacc;
    __syncthreads();
    if (tid == 0)
        gpart[blockIdx.x] = gred[0] + gred[1] + gred[2] + gred[3];
}

// ---------------------------------------------------------------------------
// Kernel 2 (v8): CHUNKED two-phase max-plus CKY. One block (512 thr) / batch.
//   A [i][k] pitch 132 : span starting at i, width k (holds pot until step k)
//   Bt[j][c] pitch 132 : c = N-1-width (k-contiguous at every step)
// Width chunks [W, W+16). For step w = W+d, k-terms split:
//   bulk  k in [d, W-1] : BOTH operands older than chunk -> computed ONCE per
//                         chunk (phase A) into registers md[16], all 512
//                         threads busy, zero barriers inside.
//   edge1 k in [0, d-1] : alo[] (registers, = A[i][0..15], fixed after chunk0)
//                         + fresh-B burst Bt[j][width W..w-1] (contig quads).
//   edge2 k in [W, w-1] : own av[] (registers, this chunk's values)
//                         + old-B burst Bt[j][width 0..d-1] (contig quads).
// Serial interval per step: <=8 broadcast b128 + ~2d fmax + 2 writes.
// Chunk 0 (w=1..15) = edge2-only steps. Bulk B-alignment S=(-d)&3 folded at
// compile time (d fully unrolled); no NEGF pads needed (bursts only use
// valid elements; bulk first-quad masked in registers).
// ---------------------------------------------------------------------------
__global__ __launch_bounds__(512, 1) void cky_kernel(
    const float* __restrict__ pot, const float* __restrict__ gpart,
    const int* __restrict__ labels, float* __restrict__ out)
{
    const int b = blockIdx.x;
    const int tid = threadIdx.x;
    const float* p = pot + (size_t)b * SEQ * SEQ;

    __shared__ __align__(16) float A[SEQ * PA];       // 67584 B
    __shared__ __align__(16) float Bt[SEQ * PA];      // 67584 B
    __shared__ int s_len;
    __shared__ float s_gold;

    if (tid < 64) {                                   // len[b]
        const size_t base = (size_t)b << 14;
        int cnt = (labels[base + tid] != -100) + (labels[base + 64 + tid] != -100);
        #pragma unroll
        for (int d = 32; d; d >>= 1) cnt += __shfl_down(cnt, d, 64);
        if (tid == 0) s_len = cnt;
    } else if (tid < 128) {                           // gold[b] from partials
        float g = gpart[b * 64 + (tid - 64)];
        #pragma unroll
        for (int d = 32; d; d >>= 1) g += __shfl_down(g, d, 64);
        if (tid == 64) s_gold = g;
    }

    {   // scatter pot into both tables (coalesced global float4 reads)
        const float4* p4 = reinterpret_cast<const float4*>(p);
        for (int qi = tid; qi < SEQ * SEQ / 4; qi += 512) {
            const int i = qi >> 5;
            const int j0 = (qi & 31) << 2;
            const float4 v = p4[qi];
            const float vv[4] = { v.x, v.y, v.z, v.w };
            #pragma unroll
            for (int c2 = 0; c2 < 4; ++c2) {
                const int j = j0 + c2;
                if (j >= i) {
                    A[i * PA + (j - i)] = vv[c2];
                    Bt[j * PA + (SEQ - 1 - (j - i))] = vv[c2];
                }
            }
        }
    }
    __syncthreads();

    const int i = tid >> 2, s = tid & 3;
    float alo[16], av[16], pv[16], md[16];

    // ---------------- chunk 0: w = 1..15 (edge2-only) ----------------
    #pragma unroll
    for (int t = 0; t < 4; ++t) {
        const float4 v = *reinterpret_cast<const float4*>(&A[i * PA + 4 * t]);
        pv[4*t] = v.x; pv[4*t+1] = v.y; pv[4*t+2] = v.z; pv[4*t+3] = v.w;
    }
    av[0] = pv[0];
    #pragma unroll
    for (int d = 1; d < 16; ++d) {
        const int j = i + d;
        if (j < SEQ) {
            float bo[16];
            const int NQ = (d + 3) >> 2;
            #pragma unroll
            for (int t = 0; t < NQ; ++t) {   // quad covers widths 4t..4t+3 (reversed)
                const float4 v = *reinterpret_cast<const float4*>(&Bt[j * PA + 124 - 4 * t]);
                bo[4*t] = v.w; bo[4*t+1] = v.z; bo[4*t+2] = v.y; bo[4*t+3] = v.x;
            }
            float val = NEGF;
            #pragma unroll
            for (int m = 0; m < d; ++m)
                val = fmaxf(val, av[d - 1 - m] + bo[m]);
            val += pv[d];
            av[d] = val;
            if (s == 0) {
                A[i * PA + d] = val;
                Bt[j * PA + (SEQ - 1 - d)] = val;
            }
        }
        __syncthreads();
    }
    #pragma unroll
    for (int k = 0; k < 16; ++k) alo[k] = av[k];

    // ---------------- chunks W = 16..112 ----------------
    for (int W = 16; W < SEQ; W += 16) {
        // pv = A[i][W..W+15] (pot values, stable until this chunk's writes)
        #pragma unroll
        for (int t = 0; t < 4; ++t) {
            const float4 v = *reinterpret_cast<const float4*>(&A[i * PA + W + 4 * t]);
            pv[4*t] = v.x; pv[4*t+1] = v.y; pv[4*t+2] = v.z; pv[4*t+3] = v.w;
        }
        #pragma unroll
        for (int d = 0; d < 16; ++d) md[d] = NEGF;

        // ---- phase A: bulk k in [d, W-1], all data pre-chunk ----
        {   // first quad (k0 = 4s <= 12): mask k >= d
            const int k0 = s << 2;
            const float4 a = *reinterpret_cast<const float4*>(&A[i * PA + k0]);
            const float aa[4] = { a.x, a.y, a.z, a.w };
            #pragma unroll
            for (int d = 0; d < 16; ++d) {
                const int j = i + W + d;
                if (j < SEQ) {
                    const float* bp = &Bt[j * PA + (SEQ - W - d) + k0];
                    float b0, b1, b2, b3;
                    if ((d & 3) == 0) {
                        const float4 v = *reinterpret_cast<const float4*>(bp);
                        b0 = v.x; b1 = v.y; b2 = v.z; b3 = v.w;
                    } else if ((d & 3) == 2) {
                        const float2 v0 = *reinterpret_cast<const float2*>(bp);
                        const float2 v1 = *reinterpret_cast<const float2*>(bp + 2);
                        b0 = v0.x; b1 = v0.y; b2 = v1.x; b3 = v1.y;
                    } else {
                        b0 = bp[0];
                        const float2 v = *reinterpret_cast<const float2*>(bp + 1);
                        b1 = v.x; b2 = v.y; b3 = bp[3];
                    }
                    const float a0 = (k0 + 0 >= d) ? aa[0] : NEGF;
                    const float a1 = (k0 + 1 >= d) ? aa[1] : NEGF;
                    const float a2 = (k0 + 2 >= d) ? aa[2] : NEGF;
                    const float a3 = (k0 + 3 >= d) ? aa[3] : NEGF;
                    md[d] = fmaxf(md[d], fmaxf(fmaxf(a0 + b0, a1 + b1),
                                               fmaxf(a2 + b2, a3 + b3)));
                }
            }
        }
        for (int q = s + 4; q < (W >> 2); q += 4) {   // k0 >= 16 > d: no masks
            const int k0 = q << 2;
            const float4 a = *reinterpret_cast<const float4*>(&A[i * PA + k0]);
            #pragma unroll
            for (int d = 0; d < 16; ++d) {
                const int j = i + W + d;
                if (j < SEQ) {
                    const float* bp = &Bt[j * PA + (SEQ - W - d) + k0];
                    float b0, b1, b2, b3;
                    if ((d & 3) == 0) {
                        const float4 v = *reinterpret_cast<const float4*>(bp);
                        b0 = v.x; b1 = v.y; b2 = v.z; b3 = v.w;
                    } else if ((d & 3) == 2) {
                        const float2 v0 = *reinterpret_cast<const float2*>(bp);
                        const float2 v1 = *reinterpret_cast<const float2*>(bp + 2);
                        b0 = v0.x; b1 = v0.y; b2 = v1.x; b3 = v1.y;
                    } else {
                        b0 = bp[0];
                        const float2 v = *reinterpret_cast<const float2*>(bp + 1);
                        b1 = v.x; b2 = v.y; b3 = bp[3];
                    }
                    md[d] = fmaxf(md[d], fmaxf(fmaxf(a.x + b0, a.y + b1),
                                               fmaxf(a.z + b2, a.w + b3)));
                }
            }
        }
        #pragma unroll
        for (int d = 0; d < 16; ++d) {    // 4-lane butterfly
            md[d] = fmaxf(md[d], __shfl_xor(md[d], 1, 4));
            md[d] = fmaxf(md[d], __shfl_xor(md[d], 2, 4));
        }

        // ---- phase B: 16 tiny serial steps ----
        #pragma unroll
        for (int d = 0; d < 16; ++d) {
            const int w = W + d;
            const int j = i + w;
            if (j < SEQ) {
                float val = md[d];
                if (d > 0) {
                    float bo[16], bf[16];
                    const int NQ = (d + 3) >> 2;
                    #pragma unroll
                    for (int t = 0; t < NQ; ++t) {
                        // old-B: widths 4t..4t+3 (reversed quad)
                        const float4 v = *reinterpret_cast<const float4*>(&Bt[j * PA + 124 - 4 * t]);
                        bo[4*t] = v.w; bo[4*t+1] = v.z; bo[4*t+2] = v.y; bo[4*t+3] = v.x;
                        // fresh-B: widths W+4t..W+4t+3 (reversed quad)
                        const float4 u = *reinterpret_cast<const float4*>(&Bt[j * PA + 124 - W - 4 * t]);
                        bf[4*t] = u.w; bf[4*t+1] = u.z; bf[4*t+2] = u.y; bf[4*t+3] = u.x;
                    }
                    #pragma unroll
                    for (int m = 0; m < d; ++m) {
                        val = fmaxf(val, av[d - 1 - m] + bo[m]);    // k in [W, w-1]
                        val = fmaxf(val, alo[d - 1 - m] + bf[m]);   // k in [0, d-1]
                    }
                }
                val += pv[d];
                av[d] = val;
                if (s == 0) {
                    A[i * PA + w] = val;
                    Bt[j * PA + (SEQ - 1 - w)] = val;
                }
            }
            __syncthreads();
        }
    }

    if (tid == 0) {
        const int len = s_len;
        const float pred = A[len - 1];        // A[0][len-1]
        const float margin = fmaxf(pred - s_gold, 0.0f);
        atomicAdd(out, margin * (1.0f / (float)BATCH));
    }
}

extern "C" void kernel_launch(void* const* d_in, const int* in_sizes, int n_in,
                              void* d_out, int out_size, void* d_ws, size_t ws_size,
                              hipStream_t stream) {
    const float* logits = (const float*)d_in[0];
    const int* labels = (const int*)d_in[1];
    float* out = (float*)d_out;

    float* pot = (float*)d_ws;                          // B*N*N floats = 4 MB
    float* gpart = pot + (size_t)BATCH * SEQ * SEQ;     // 4096 floats

    (void)hipMemsetAsync(out, 0, sizeof(float), stream);

    pot_gold_kernel<<<BATCH * SEQ * SEQ / 256, 256, 0, stream>>>(
        logits, labels, pot, gpart);
    cky_kernel<<<BATCH, 512, 0, stream>>>(pot, gpart, labels, out);
}